// Round 14
// baseline (36.612 us; speedup 1.0000x reference)
//
#include <hip/hip_runtime.h>
#include <hip/hip_bf16.h>

#define LOG2E_F 1.4426950408889634f

typedef __attribute__((ext_vector_type(8))) short short8;
typedef __attribute__((ext_vector_type(4))) float f32x4;
typedef __attribute__((ext_vector_type(2))) float f32x2;

__device__ inline unsigned short f2b(float f) {
    __hip_bfloat16 h = __float2bfloat16(f);   // RNE
    return *reinterpret_cast<unsigned short*>(&h);
}

__device__ inline short8 load_frag_f32(const float* p) {
    const float4 lo = *(const float4*)p;
    const float4 hi = *(const float4*)(p + 4);
    short8 r;
    r[0] = (short)f2b(lo.x); r[1] = (short)f2b(lo.y);
    r[2] = (short)f2b(lo.z); r[3] = (short)f2b(lo.w);
    r[4] = (short)f2b(hi.x); r[5] = (short)f2b(hi.y);
    r[6] = (short)f2b(hi.z); r[7] = (short)f2b(hi.w);
    return r;
}

__device__ inline f32x2 mk2(float a, float b) { f32x2 r; r.x = a; r.y = b; return r; }
// unpack a u32 holding two bf16 (lo=elem0, hi=elem1) into f32x2
__device__ inline f32x2 bfup(unsigned u) {
    return mk2(__uint_as_float(u << 16), __uint_as_float(u & 0xffff0000u));
}
#define PK_FMA(a, b, c) __builtin_elementwise_fma((a), (b), (c))

// =====================================================================
// Prologue: one-time f32 -> bf16 conversion of x, Win, Wout (R13).
// =====================================================================
__global__ __launch_bounds__(256) void prep_kernel(
    const float* __restrict__ x, const float* __restrict__ Win,
    const float* __restrict__ Wout,
    unsigned short* __restrict__ xbf, unsigned short* __restrict__ winbf,
    unsigned short* __restrict__ woutbf)
{
    const int i = blockIdx.x * 256 + threadIdx.x;   // unit = 8 floats
    const float* src; unsigned short* dst; size_t off;
    if (i < 262144)       { src = x;    dst = xbf;    off = (size_t)i * 8; }
    else if (i < 268288)  { src = Win;  dst = winbf;  off = (size_t)(i - 262144) * 8; }
    else                  { src = Wout; dst = woutbf; off = (size_t)(i - 268288) * 8; }
    const short8 r = load_frag_f32(src + off);
    *(short8*)(dst + off) = r;
}

// =====================================================================
// Fused layer (R13 structure: 256 blocks = 1/CU, 512 thr = 2 systems).
// R14 changes: (a) k/v stored BF16 in LDS [kj][h][16] -> phase-2 K/V
// reads 8->4 ds_read_b128 per kj (per-CU LDS delivery halved: the
// measured dominant shared-pipe cost), unpack via 1 shift/and per elem;
// (b) lattice LSE without min-shift: ssum = sum_r exp2(al2*d2_r) is
// exact-safe (args in [-52,0], no subnormals), removing the 12-op
// min/c0 chain per kj. p = exp2(dot-16)*ssum (fixed-shift softmax).
// =====================================================================
__global__ __launch_bounds__(512, 2) void fused2_kernel(
    const unsigned short* __restrict__ xbf, const unsigned short* __restrict__ winbf,
    const float* __restrict__ bin, const unsigned short* __restrict__ woutbf,
    const float* __restrict__ bout, const float* __restrict__ alpha,
    const float* __restrict__ dist2, float* __restrict__ out)
{
    __shared__ float qf[2][32][164];                  // 42.0 KB (f32 q, pad 164)
    __shared__ unsigned short kvb[2][2][32][8][16];   // 32.0 KB (bf16 k/v)
    __shared__ unsigned short aggb[2][32][136];       // 17.0 KB

    const int tid  = threadIdx.x;                // 0..511
    const int g    = tid >> 8;                   // system group 0/1
    const int t    = tid & 255;
    const int sys  = blockIdx.x * 2 + g;
    const int lane = t & 63;
    const int wv   = t >> 6;                     // wave within group, 0..3
    const int r16  = lane & 15;
    const int kg   = lane >> 4;
    const int base = sys << 5;

    // ---------------- Phase 1: QKV projection into LDS[g] --------------
    short8 af[2][4];
    #pragma unroll
    for (int rt = 0; rt < 2; ++rt)
        #pragma unroll
        for (int ks = 0; ks < 4; ++ks)
            af[rt][ks] = *(const short8*)(
                xbf + (size_t)(base + rt * 16 + r16) * 128 + ks * 32 + kg * 8);

    #pragma unroll
    for (int j = 0; j < 6; ++j) {
        const int ct = wv * 6 + j;            // 0..23 (wave-uniform)
        const int c  = ct * 16 + r16;         // global col 0..383
        short8 bf[4];
        #pragma unroll
        for (int ks = 0; ks < 4; ++ks)
            bf[ks] = *(const short8*)(winbf + (size_t)c * 128 + ks * 32 + kg * 8);
        const float bias_v = bin[c];
        const int   bufi   = ct >> 3;         // 0=q, 1=k, 2=v
        const int   hh     = ct & 7;

        #pragma unroll
        for (int rt = 0; rt < 2; ++rt) {
            f32x4 acc = {0.f, 0.f, 0.f, 0.f};
            #pragma unroll
            for (int ks = 0; ks < 4; ++ks)
                acc = __builtin_amdgcn_mfma_f32_16x16x32_bf16(af[rt][ks], bf[ks], acc, 0, 0, 0);
            // C/D: col = lane&15 (=r16 -> feature), row = kg*4+r (-> atom)
            #pragma unroll
            for (int r = 0; r < 4; ++r) {
                const int atom = rt * 16 + kg * 4 + r;
                const float v  = acc[r] + bias_v;
                if (bufi == 0)
                    qf[g][atom][hh * 20 + r16] = v * (0.25f * LOG2E_F);
                else
                    kvb[g][bufi - 1][atom][hh][r16] = f2b(v);
            }
        }
    }

    const int qi = t >> 3;
    const int h  = t & 7;
    const float al2 = alpha[(size_t)(base + qi) * 8 + h] * LOG2E_F;   // < 0
    const f32x2 al22 = mk2(al2, al2);

    __syncthreads();

    // ---------------- Phase 2: attention (bf16 K/V, packed math) -------
    f32x2 q2[8];
    {
        const float* qrow = &qf[g][qi][h * 20];
        #pragma unroll
        for (int d4 = 0; d4 < 4; ++d4) {
            const float4 tq = *(const float4*)(qrow + (d4 << 2));
            q2[d4 * 2 + 0] = mk2(tq.x, tq.y);
            q2[d4 * 2 + 1] = mk2(tq.z, tq.w);
        }
    }

    float den = 0.f;
    f32x2 acc2[8] = {};
    const float* dp = dist2 + (size_t)(sys * 1024 + qi * 32) * 16;

    #pragma unroll 4
    for (int kj = 0; kj < 32; ++kj, dp += 16) {
        // ---- lattice sum, no shift: args al2*d2 in [-52,0] are exp2-safe
        const float4 t0 = *(const float4*)(dp + 0);
        const float4 t1 = *(const float4*)(dp + 4);
        const float4 t2 = *(const float4*)(dp + 8);
        const float4 t3 = *(const float4*)(dp + 12);
        const f32x2 d2p[8] = {mk2(t0.x,t0.y), mk2(t0.z,t0.w), mk2(t1.x,t1.y), mk2(t1.z,t1.w),
                              mk2(t2.x,t2.y), mk2(t2.z,t2.w), mk2(t3.x,t3.y), mk2(t3.z,t3.w)};
        f32x2 es;
        {
            const f32x2 a0 = al22 * d2p[0];
            es = mk2(__builtin_amdgcn_exp2f(a0.x), __builtin_amdgcn_exp2f(a0.y));
            #pragma unroll
            for (int i = 1; i < 8; ++i) {
                const f32x2 a = al22 * d2p[i];
                es += mk2(__builtin_amdgcn_exp2f(a.x), __builtin_amdgcn_exp2f(a.y));
            }
        }
        const float ssum = es.x + es.y;              // in (0, 16]

        // ---- q.k dot: bf16 K row (2 x b128) unpacked to f32x2 ----
        const uint4* krp = (const uint4*)&kvb[g][0][kj][h][0];
        const uint4 ka = krp[0];
        const uint4 kb = krp[1];
        f32x2 dA = q2[0] * bfup(ka.x);
        f32x2 dB = q2[1] * bfup(ka.y);
        dA = PK_FMA(q2[2], bfup(ka.z), dA);
        dB = PK_FMA(q2[3], bfup(ka.w), dB);
        dA = PK_FMA(q2[4], bfup(kb.x), dA);
        dB = PK_FMA(q2[5], bfup(kb.y), dB);
        dA = PK_FMA(q2[6], bfup(kb.z), dA);
        dB = PK_FMA(q2[7], bfup(kb.w), dB);
        const float dot = (dA.x + dA.y) + (dB.x + dB.y);   // log2-domain

        // fixed-shift softmax (R8-R13 validated)
        const float p = __builtin_amdgcn_exp2f(dot - 16.0f) * ssum;
        den += p;
        const f32x2 p2 = mk2(p, p);

        // ---- PV accumulate: bf16 V row unpacked ----
        const uint4* vrp = (const uint4*)&kvb[g][1][kj][h][0];
        const uint4 va = vrp[0];
        const uint4 vb = vrp[1];
        acc2[0] = PK_FMA(p2, bfup(va.x), acc2[0]);
        acc2[1] = PK_FMA(p2, bfup(va.y), acc2[1]);
        acc2[2] = PK_FMA(p2, bfup(va.z), acc2[2]);
        acc2[3] = PK_FMA(p2, bfup(va.w), acc2[3]);
        acc2[4] = PK_FMA(p2, bfup(vb.x), acc2[4]);
        acc2[5] = PK_FMA(p2, bfup(vb.y), acc2[5]);
        acc2[6] = PK_FMA(p2, bfup(vb.z), acc2[6]);
        acc2[7] = PK_FMA(p2, bfup(vb.w), acc2[7]);
    }

    // write normalized agg row (bf16) to LDS[g]
    {
        const float inv = 1.0f / den;
        const f32x2 inv2 = mk2(inv, inv);
        unsigned short* op = &aggb[g][qi][h * 16];
        uint4 o0, o1;
        f32x2 r0 = acc2[0] * inv2, r1 = acc2[1] * inv2;
        f32x2 r2 = acc2[2] * inv2, r3 = acc2[3] * inv2;
        f32x2 r4 = acc2[4] * inv2, r5 = acc2[5] * inv2;
        f32x2 r6 = acc2[6] * inv2, r7 = acc2[7] * inv2;
        o0.x = (unsigned)f2b(r0.x) | ((unsigned)f2b(r0.y) << 16);
        o0.y = (unsigned)f2b(r1.x) | ((unsigned)f2b(r1.y) << 16);
        o0.z = (unsigned)f2b(r2.x) | ((unsigned)f2b(r2.y) << 16);
        o0.w = (unsigned)f2b(r3.x) | ((unsigned)f2b(r3.y) << 16);
        o1.x = (unsigned)f2b(r4.x) | ((unsigned)f2b(r4.y) << 16);
        o1.y = (unsigned)f2b(r5.x) | ((unsigned)f2b(r5.y) << 16);
        o1.z = (unsigned)f2b(r6.x) | ((unsigned)f2b(r6.y) << 16);
        o1.w = (unsigned)f2b(r7.x) | ((unsigned)f2b(r7.y) << 16);
        *(uint4*)op       = o0;
        *(uint4*)(op + 8) = o1;
    }

    __syncthreads();

    // ---------------- Phase 3: out-projection --------------------------
    short8 aA[2][4];
    #pragma unroll
    for (int rt = 0; rt < 2; ++rt)
        #pragma unroll
        for (int ks = 0; ks < 4; ++ks)
            aA[rt][ks] = *(const short8*)(&aggb[g][rt * 16 + r16][ks * 32 + kg * 8]);

    #pragma unroll
    for (int j = 0; j < 2; ++j) {
        const int ct = wv * 2 + j;            // 0..7
        const int c  = ct * 16 + r16;         // 0..127
        short8 bf[4];
        #pragma unroll
        for (int ks = 0; ks < 4; ++ks)
            bf[ks] = *(const short8*)(woutbf + (size_t)c * 128 + ks * 32 + kg * 8);
        const float bias_v = bout[c];
        #pragma unroll
        for (int rt = 0; rt < 2; ++rt) {
            f32x4 oacc = {0.f, 0.f, 0.f, 0.f};
            #pragma unroll
            for (int ks = 0; ks < 4; ++ks)
                oacc = __builtin_amdgcn_mfma_f32_16x16x32_bf16(aA[rt][ks], bf[ks], oacc, 0, 0, 0);
            #pragma unroll
            for (int r = 0; r < 4; ++r) {
                const int row = base + rt * 16 + kg * 4 + r;
                out[(size_t)row * 128 + c] = oacc[r] + bias_v;
            }
        }
    }
}

// =====================================================================
extern "C" void kernel_launch(void* const* d_in, const int* in_sizes, int n_in,
                              void* d_out, int out_size, void* d_ws, size_t ws_size,
                              hipStream_t stream)
{
    const float* x     = (const float*)d_in[0];   // [16384,128]
    const float* Win   = (const float*)d_in[1];   // [384,128]
    const float* bin   = (const float*)d_in[2];   // [384]
    const float* Wout  = (const float*)d_in[3];   // [128,128]
    const float* bout  = (const float*)d_in[4];   // [128]
    const float* alpha = (const float*)d_in[5];   // [16384,8]
    const float* dist2 = (const float*)d_in[6];   // [524288,16]

    unsigned short* xbf    = (unsigned short*)d_ws;            // 4 MB
    unsigned short* winbf  = xbf + (size_t)16384 * 128;        // 96 KB
    unsigned short* woutbf = winbf + (size_t)384 * 128;        // 32 KB

    prep_kernel<<<dim3(1056), 256, 0, stream>>>(x, Win, Wout, xbf, winbf, woutbf);
    fused2_kernel<<<dim3(256), 512, 0, stream>>>(
        xbf, winbf, bin, woutbf, bout, alpha, dist2, (float*)d_out);
}